// Round 1
// baseline (1344.612 us; speedup 1.0000x reference)
//
#include <hip/hip_runtime.h>
#include <hip/hip_fp16.h>

// Problem: S=2048, B=32, H=1024.
// out[b][s] = softmax_s( sum_h tanh( (enc[s][b] @ We)[h] + hproj[b][h] ) * v[h] )
// hproj = hidden @ Wh + bias.  Wh = W[0:1024], We = W[1024:3072].
//
// Big GEMM: M = S*B = 65536 (enc rows, K-contiguous), K = 2048, N = 1024.
// fp16 MFMA (16x16x32) with f32 accumulate; fused tanh/dot-v epilogue;
// per-ntile partial scores -> softmax kernel.

typedef _Float16 half8 __attribute__((ext_vector_type(8)));
typedef float floatx4 __attribute__((ext_vector_type(4)));

constexpr int SEQ = 2048;
constexpr int BAT = 32;
constexpr int HID = 1024;
constexpr int KDIM = 2048;        // 2H
constexpr int MTOT = SEQ * BAT;   // 65536
constexpr int NT = 8;             // N tiles of 128
constexpr int KT = 64;            // K tiles of 32

// ---------------------------------------------------------------------------
// Pack We (f32, rows e=0..2047 of W offset by 1024, row-major [e][h]) into
// fp16 chunks ordered exactly as the GEMM staging consumes them:
// packB[((nt*64 + kt)*512 + c)*8 + j] = We[kt*32 + (c>>7)*8 + j][nt*128 + (c&127)]
// ---------------------------------------------------------------------------
__global__ __launch_bounds__(256) void pack_b_kernel(const float* __restrict__ W,
                                                     _Float16* __restrict__ pb) {
    int t = blockIdx.x * blockDim.x + threadIdx.x;   // 0..262143
    int nt = t >> 15;
    int rem = t & 32767;
    int kt = rem >> 9;
    int c = rem & 511;
    int g = c >> 7;
    int n = c & 127;
    int h = nt * 128 + n;
    int e0 = kt * 32 + g * 8;
    const float* src = W + (size_t)(1024 + e0) * 1024 + h;
    union { _Float16 hh[8]; uint4 u; } tmp;
#pragma unroll
    for (int j = 0; j < 8; ++j) tmp.hh[j] = (_Float16)src[(size_t)j * 1024];
    *(uint4*)(pb + (size_t)t * 8) = tmp.u;
}

// ---------------------------------------------------------------------------
// hproj[b][h] = sum_e hidden[b][e] * W[e][h] + bias[h]   (f32, tiny GEMM)
// ---------------------------------------------------------------------------
__global__ __launch_bounds__(256) void hproj_kernel(const float* __restrict__ hidden,
                                                    const float* __restrict__ W,
                                                    const float* __restrict__ bias,
                                                    float* __restrict__ hp) {
    int b = blockIdx.x;
    int h = blockIdx.y * 256 + threadIdx.x;
    const float* hrow = hidden + b * HID;
    const float* wc = W + h;
    float acc = bias[h];
#pragma unroll 8
    for (int e = 0; e < HID; ++e) acc += hrow[e] * wc[(size_t)e * HID];
    hp[b * HID + h] = acc;
}

// ---------------------------------------------------------------------------
// Main fused GEMM + tanh + dot(v) kernel.
// Block = 256 threads (4 waves), tile 128(M) x 128(N), BK=32.
// LDS A: 4 g-blocks of (128 rows * 16B) + 16B pad each (bank spread).
// LDS B: 512 chunks of 16B, chunk c = g*128 + n  (written in lane order).
// ---------------------------------------------------------------------------
constexpr int APITCH = 128 * 16 + 16;   // 2064 bytes per g-block

__global__ __launch_bounds__(256) void attn_gemm_kernel(
    const float* __restrict__ enc, const _Float16* __restrict__ pb,
    const float* __restrict__ hp, const float* __restrict__ v,
    float* __restrict__ partial) {
    __shared__ char smem[4 * APITCH + 512 * 16];
    char* sA = smem;
    char* sB = smem + 4 * APITCH;

    const int nt = blockIdx.x;
    const int mt = blockIdx.y;
    const int r0 = mt * 128;
    const int n0 = nt * 128;
    const int tid = threadIdx.x;
    const int lane = tid & 63;
    const int wave = tid >> 6;
    const int wm = wave & 1;    // M half (0/1)
    const int wn = wave >> 1;   // N half (0/1)

    // ---- A staging mapping: thread -> (row base, k-chunk) -------------------
    // Per iter i (0..3): row = (tid>>3) + i*32, covers 128 rows.
    // k-offset (f32) = (tid&7)*4 -> fully coalesced float4 loads (8 rows x 128B).
    const int arow = tid >> 3;          // 0..31
    const int au = tid & 7;
    const int ag = au >> 1;             // g chunk 0..3
    const int ahalf = au & 1;           // which 8B half of the 16B chunk
    const float* aptr = enc + (size_t)(r0 + arow) * KDIM + au * 4;
    char* awr = sA + ag * APITCH + arow * 16 + ahalf * 8;

    // ---- B staging: packed fp16 chunks, contiguous per (nt,kt) --------------
    const uint4* bptr = (const uint4*)pb + (size_t)nt * KT * 512 + tid;
    uint4* bwr = (uint4*)sB + tid;

    // ---- fragment read offsets ---------------------------------------------
    const int fm = lane & 15;
    const int fg = lane >> 4;
    const char* ard = sA + fg * APITCH + (wm * 64 + fm) * 16;
    const char* brd = sB + (fg * 128 + wn * 64 + fm) * 16;

    floatx4 acc[4][4];
#pragma unroll
    for (int i = 0; i < 4; ++i)
#pragma unroll
        for (int j = 0; j < 4; ++j) acc[i][j] = (floatx4)0.0f;

    for (int kt = 0; kt < KT; ++kt) {
        __syncthreads();
        // stage A: f32 -> f16 (RNE) through registers
#pragma unroll
        for (int i = 0; i < 4; ++i) {
            float4 f = *(const float4*)(aptr + kt * 32 + (size_t)i * 32 * KDIM);
            union { _Float16 hh[4]; uint2 u; } pk;
            pk.hh[0] = (_Float16)f.x;
            pk.hh[1] = (_Float16)f.y;
            pk.hh[2] = (_Float16)f.z;
            pk.hh[3] = (_Float16)f.w;
            *(uint2*)(awr + i * 32 * 16) = pk.u;
        }
        // stage B: already fp16, contiguous
        uint4 b0 = bptr[(size_t)kt * 512];
        uint4 b1 = bptr[(size_t)kt * 512 + 256];
        bwr[0] = b0;
        bwr[256] = b1;
        __syncthreads();

        half8 af[4], bf[4];
#pragma unroll
        for (int i = 0; i < 4; ++i) af[i] = *(const half8*)(ard + i * 16 * 16);
#pragma unroll
        for (int j = 0; j < 4; ++j) bf[j] = *(const half8*)(brd + j * 16 * 16);
#pragma unroll
        for (int i = 0; i < 4; ++i)
#pragma unroll
            for (int j = 0; j < 4; ++j)
                acc[i][j] = __builtin_amdgcn_mfma_f32_16x16x32_f16(af[i], bf[j], acc[i][j], 0, 0, 0);
    }

    // ---- epilogue: tanh(acc + hproj) * v, reduce over N ---------------------
    // C layout (16x16): col = lane&15, row = (lane>>4)*4 + reg
    const int rowq = (lane >> 4) * 4;
    const int col = lane & 15;
    float sums[4][4];
#pragma unroll
    for (int i = 0; i < 4; ++i)
#pragma unroll
        for (int r = 0; r < 4; ++r) sums[i][r] = 0.0f;

#pragma unroll
    for (int j = 0; j < 4; ++j) {
        int h = n0 + wn * 64 + j * 16 + col;
        float vv = v[h];
#pragma unroll
        for (int i = 0; i < 4; ++i) {
#pragma unroll
            for (int r = 0; r < 4; ++r) {
                int rowl = wm * 64 + i * 16 + rowq + r;   // row within block
                int b = rowl & 31;                        // r0 % 32 == 0
                float x = acc[i][j][r] + hp[b * HID + h];
                float e2 = __expf(2.0f * x);              // tanh = 1 - 2/(e^2x+1)
                float th = 1.0f - 2.0f / (e2 + 1.0f);
                sums[i][r] += th * vv;
            }
        }
    }
    // reduce across the 16 column-lanes
#pragma unroll
    for (int i = 0; i < 4; ++i)
#pragma unroll
        for (int r = 0; r < 4; ++r) {
            float s = sums[i][r];
            s += __shfl_xor(s, 1);
            s += __shfl_xor(s, 2);
            s += __shfl_xor(s, 4);
            s += __shfl_xor(s, 8);
            sums[i][r] = s;
        }
    __syncthreads();                 // LDS frag reads done; reuse smem
    float* red = (float*)smem;
    if (col == 0) {
#pragma unroll
        for (int i = 0; i < 4; ++i)
#pragma unroll
            for (int r = 0; r < 4; ++r)
                red[wn * 128 + wm * 64 + i * 16 + rowq + r] = sums[i][r];
    }
    __syncthreads();
    if (tid < 128) {
        float tot = red[tid] + red[128 + tid];
        partial[(size_t)nt * MTOT + r0 + tid] = tot;   // row r = s*32 + b
    }
}

// ---------------------------------------------------------------------------
// Softmax over s (2048) per batch b (32). Folds the 8 ntile partials.
// ---------------------------------------------------------------------------
__global__ __launch_bounds__(256) void softmax_kernel(const float* __restrict__ partial,
                                                      float* __restrict__ out) {
    int b = blockIdx.x;
    int tid = threadIdx.x;
    __shared__ float redm[4];
    __shared__ float reds[4];
    float vals[8];
    float mx = -1e30f;
#pragma unroll
    for (int k = 0; k < 8; ++k) {
        int s = k * 256 + tid;
        float a = 0.0f;
#pragma unroll
        for (int nt = 0; nt < 8; ++nt) a += partial[(size_t)nt * MTOT + s * 32 + b];
        vals[k] = a;
        mx = fmaxf(mx, a);
    }
    for (int d = 1; d < 64; d <<= 1) mx = fmaxf(mx, __shfl_xor(mx, d));
    int wv = tid >> 6;
    if ((tid & 63) == 0) redm[wv] = mx;
    __syncthreads();
    mx = fmaxf(fmaxf(redm[0], redm[1]), fmaxf(redm[2], redm[3]));
    float sum = 0.0f;
#pragma unroll
    for (int k = 0; k < 8; ++k) {
        vals[k] = __expf(vals[k] - mx);
        sum += vals[k];
    }
    for (int d = 1; d < 64; d <<= 1) sum += __shfl_xor(sum, d);
    if ((tid & 63) == 0) reds[wv] = sum;
    __syncthreads();
    sum = reds[0] + reds[1] + reds[2] + reds[3];
    float inv = 1.0f / sum;
#pragma unroll
    for (int k = 0; k < 8; ++k) out[b * SEQ + k * 256 + tid] = vals[k] * inv;
}

// ---------------------------------------------------------------------------
extern "C" void kernel_launch(void* const* d_in, const int* in_sizes, int n_in,
                              void* d_out, int out_size, void* d_ws, size_t ws_size,
                              hipStream_t stream) {
    const float* hidden = (const float*)d_in[0];
    const float* enc    = (const float*)d_in[1];
    const float* W      = (const float*)d_in[2];
    const float* bias   = (const float*)d_in[3];
    const float* v      = (const float*)d_in[4];
    float* out = (float*)d_out;

    char* ws = (char*)d_ws;
    _Float16* packB = (_Float16*)ws;                              // 4 MiB
    float* hp       = (float*)(ws + (4u << 20));                  // 128 KiB
    float* partial  = (float*)(ws + (4u << 20) + (128u << 10));   // 2 MiB

    pack_b_kernel<<<1024, 256, 0, stream>>>(W, packB);
    hproj_kernel<<<dim3(32, 4), 256, 0, stream>>>(hidden, W, bias, hp);
    attn_gemm_kernel<<<dim3(NT, MTOT / 128), 256, 0, stream>>>(enc, packB, hp, v, partial);
    softmax_kernel<<<BAT, 256, 0, stream>>>(partial, out);
}

// Round 2
// 1075.001 us; speedup vs baseline: 1.2508x; 1.2508x over previous
//
#include <hip/hip_runtime.h>
#include <hip/hip_fp16.h>

// S=2048, B=32, H=1024.
// out[b][s] = softmax_s( sum_h tanh( (enc[s][b] @ We)[h] + hproj[b][h] ) * v[h] )
//
// GEMM: M = 65536 rows (K-contiguous), K = 2048, N = 1024.
// Block = 512 threads (8 waves) owns a 64-row M-slab and ALL of N:
//   wave w computes nt=w (128 cols), acc 4(m) x 8(n) frags.
// A (enc f32) is read from HBM exactly once; B (packed fp16 We, 4 MB) is
// L2-resident and re-read per block. Double-buffered LDS, global_load_lds
// for B, register-cvt staging for A (padded LDS -> conflict-light frags).

typedef _Float16 half8 __attribute__((ext_vector_type(8)));
typedef float floatx4 __attribute__((ext_vector_type(4)));
typedef float f32x4 __attribute__((ext_vector_type(4)));

constexpr int SEQ = 2048;
constexpr int BAT = 32;
constexpr int HID = 1024;
constexpr int KDIM = 2048;
constexpr int MTOT = SEQ * BAT;   // 65536
constexpr int KT = 64;            // K tiles of 32

constexpr int B_BUF = 65536;          // 8 nt * 512 chunks * 16B
constexpr int A_PITCH = 64 * 16 + 16; // 1040 B per fg group (pad breaks bank alias)
constexpr int A_BUF = 4 * A_PITCH;    // 4160

__device__ __forceinline__ void glds16(const void* g, void* l) {
    __builtin_amdgcn_global_load_lds((__attribute__((address_space(1))) void*)(g),
                                     (__attribute__((address_space(3))) void*)(l), 16, 0, 0);
}

// ---------------------------------------------------------------------------
// Pack We into fp16 chunks: packB[((nt*64+kt)*512 + fg*128 + n)*8 + j]
//   = We[kt*32 + fg*8 + j][nt*128 + n]
// ---------------------------------------------------------------------------
__global__ __launch_bounds__(256) void pack_b_kernel(const float* __restrict__ W,
                                                     _Float16* __restrict__ pb) {
    int t = blockIdx.x * blockDim.x + threadIdx.x;   // 0..262143
    int nt = t >> 15;
    int rem = t & 32767;
    int kt = rem >> 9;
    int c = rem & 511;
    int g = c >> 7;
    int n = c & 127;
    int h = nt * 128 + n;
    int e0 = kt * 32 + g * 8;
    const float* src = W + (size_t)(1024 + e0) * 1024 + h;
    union { _Float16 hh[8]; uint4 u; } tmp;
#pragma unroll
    for (int j = 0; j < 8; ++j) tmp.hh[j] = (_Float16)src[(size_t)j * 1024];
    *(uint4*)(pb + (size_t)t * 8) = tmp.u;
}

// ---------------------------------------------------------------------------
// hproj[b][h] = hidden[b] . W[:,h] + bias[h]. 4-way K-split, 512 blocks.
// ---------------------------------------------------------------------------
__global__ __launch_bounds__(256) void hproj_kernel(const float* __restrict__ hidden,
                                                    const float* __restrict__ W,
                                                    const float* __restrict__ bias,
                                                    float* __restrict__ hp) {
    int b = blockIdx.x;                 // 0..31
    int h0 = blockIdx.y * 64;           // 16 y-blocks
    int hl = threadIdx.x & 63;
    int ks = threadIdx.x >> 6;          // 0..3
    const float* hr = hidden + b * HID + ks * 256;
    const float* wc = W + (size_t)(ks * 256) * HID + h0 + hl;
    float acc = 0.0f;
#pragma unroll 8
    for (int e = 0; e < 256; ++e) acc += hr[e] * wc[(size_t)e * HID];
    __shared__ float red[256];
    red[threadIdx.x] = acc;
    __syncthreads();
    if (threadIdx.x < 64)
        hp[b * HID + h0 + threadIdx.x] = red[threadIdx.x] + red[64 + threadIdx.x] +
                                         red[128 + threadIdx.x] + red[192 + threadIdx.x] +
                                         bias[h0 + threadIdx.x];
}

// ---------------------------------------------------------------------------
// Main fused kernel.
// ---------------------------------------------------------------------------
__global__ __launch_bounds__(512, 2) void attn_gemm_kernel(
    const float* __restrict__ enc, const _Float16* __restrict__ pb,
    const float* __restrict__ hp, const float* __restrict__ v,
    float* __restrict__ score) {
    __shared__ char smem[2 * B_BUF + 2 * A_BUF];
    char* sB0 = smem;
    char* sB1 = smem + B_BUF;
    char* sA0 = smem + 2 * B_BUF;
    char* sA1 = smem + 2 * B_BUF + A_BUF;

    const int tid = threadIdx.x;
    const int lane = tid & 63;
    const int wv = tid >> 6;            // 0..7 == nt
    const int mt = blockIdx.x;          // 0..1023
    const size_t r0 = (size_t)mt * 64;
    const int fm = lane & 15;
    const int fg = lane >> 4;

    // B staging: wave wv stages nt=wv. 8 glds16 per thread per kt.
    const char* bg = (const char*)pb + (size_t)wv * KT * 8192;
    const int bl_off = wv * 8192;

    // A staging: thread loads one float4 of the 64x32 f32 tile per kt.
    const int arow = tid >> 3;          // 0..63
    const int ac4 = tid & 7;            // float4 col
    const f32x4* agp = (const f32x4*)(enc + (r0 + arow) * KDIM) + ac4;
    const int awoff = (ac4 >> 1) * A_PITCH + arow * 16 + (ac4 & 1) * 8;

    // Fragment read offsets.
    const int ardoff = fg * A_PITCH + fm * 16;
    const int brdoff = wv * 8192 + fg * 2048 + fm * 16;

    floatx4 acc[4][8];
#pragma unroll
    for (int i = 0; i < 4; ++i)
#pragma unroll
        for (int j = 0; j < 8; ++j) acc[i][j] = (floatx4)0.0f;

    // ---- prologue: stage kt=0 into buffer 0 --------------------------------
    {
        const char* g = bg;
        char* l0 = sB0 + bl_off;
#pragma unroll
        for (int j = 0; j < 8; ++j)
            glds16(g + (j * 64 + lane) * 16, l0 + (j * 64 + lane) * 16);
        f32x4 f = __builtin_nontemporal_load(agp);
        union { _Float16 hh[4]; uint2 u; } pk;
        pk.hh[0] = (_Float16)f.x; pk.hh[1] = (_Float16)f.y;
        pk.hh[2] = (_Float16)f.z; pk.hh[3] = (_Float16)f.w;
        *(uint2*)(sA0 + awoff) = pk.u;
    }

    for (int kt = 0; kt < KT; ++kt) {
        const int cur = kt & 1;
        __syncthreads();   // drains glds(kt) [vmcnt] + A writes(kt) [lgkm]; guards buf reuse
        if (kt + 1 < KT) {
            char* sBn = (cur ? sB0 : sB1);
            char* sAn = (cur ? sA0 : sA1);
            const char* g = bg + (size_t)(kt + 1) * 8192;
            char* l0 = sBn + bl_off;
#pragma unroll
            for (int j = 0; j < 8; ++j)
                glds16(g + (j * 64 + lane) * 16, l0 + (j * 64 + lane) * 16);
            f32x4 f = __builtin_nontemporal_load(agp + (kt + 1) * 8);
            union { _Float16 hh[4]; uint2 u; } pk;
            pk.hh[0] = (_Float16)f.x; pk.hh[1] = (_Float16)f.y;
            pk.hh[2] = (_Float16)f.z; pk.hh[3] = (_Float16)f.w;
            *(uint2*)(sAn + awoff) = pk.u;
        }
        const char* ab = cur ? sA1 : sA0;
        const char* bb = cur ? sB1 : sB0;
        half8 af[4];
#pragma unroll
        for (int i = 0; i < 4; ++i) af[i] = *(const half8*)(ab + ardoff + i * 256);
#pragma unroll
        for (int j = 0; j < 8; ++j) {
            half8 bf = *(const half8*)(bb + brdoff + j * 256);
#pragma unroll
            for (int i = 0; i < 4; ++i)
                acc[i][j] = __builtin_amdgcn_mfma_f32_16x16x32_f16(af[i], bf, acc[i][j], 0, 0, 0);
        }
    }

    // ---- epilogue: tanh(acc + hproj)*v, reduce over all 1024 cols ----------
    // C layout: col = fm, row(frag) = fg*4 + r.  acc[i][j] covers rows i*16+..,
    // cols (wv*128 + j*16 + ..).
    float sums[4][4];
#pragma unroll
    for (int i = 0; i < 4; ++i)
#pragma unroll
        for (int r = 0; r < 4; ++r) sums[i][r] = 0.0f;

#pragma unroll
    for (int j = 0; j < 8; ++j) {
        int h = wv * 128 + j * 16 + fm;
        float vv = v[h];
#pragma unroll
        for (int i = 0; i < 4; ++i) {
#pragma unroll
            for (int r = 0; r < 4; ++r) {
                int row = i * 16 + fg * 4 + r;     // 0..63 within slab
                int b = row & 31;                  // r0 % 32 == 0
                float x = acc[i][j][r] + hp[b * HID + h];
                float e2 = __expf(2.0f * x);
                float th = 1.0f - 2.0f / (e2 + 1.0f);
                sums[i][r] += th * vv;
            }
        }
    }
#pragma unroll
    for (int i = 0; i < 4; ++i)
#pragma unroll
        for (int r = 0; r < 4; ++r) {
            float s = sums[i][r];
            s += __shfl_xor(s, 1);
            s += __shfl_xor(s, 2);
            s += __shfl_xor(s, 4);
            s += __shfl_xor(s, 8);
            sums[i][r] = s;
        }
    __syncthreads();                    // done with frag LDS; reuse as reduction
    float* red = (float*)smem;
    if (fm == 0) {
#pragma unroll
        for (int i = 0; i < 4; ++i)
#pragma unroll
            for (int r = 0; r < 4; ++r)
                red[wv * 64 + i * 16 + fg * 4 + r] = sums[i][r];
    }
    __syncthreads();
    if (tid < 64) {
        float tot = 0.0f;
#pragma unroll
        for (int w = 0; w < 8; ++w) tot += red[w * 64 + tid];
        score[r0 + tid] = tot;          // row m = s*32 + b
    }
}

// ---------------------------------------------------------------------------
// Softmax over s per batch b.
// ---------------------------------------------------------------------------
__global__ __launch_bounds__(256) void softmax_kernel(const float* __restrict__ score,
                                                      float* __restrict__ out) {
    int b = blockIdx.x;
    int tid = threadIdx.x;
    __shared__ float redm[4];
    __shared__ float reds[4];
    float vals[8];
    float mx = -1e30f;
#pragma unroll
    for (int k = 0; k < 8; ++k) {
        int s = k * 256 + tid;
        float a = score[(size_t)s * 32 + b];
        vals[k] = a;
        mx = fmaxf(mx, a);
    }
    for (int d = 1; d < 64; d <<= 1) mx = fmaxf(mx, __shfl_xor(mx, d));
    int wv = tid >> 6;
    if ((tid & 63) == 0) redm[wv] = mx;
    __syncthreads();
    mx = fmaxf(fmaxf(redm[0], redm[1]), fmaxf(redm[2], redm[3]));
    float sum = 0.0f;
#pragma unroll
    for (int k = 0; k < 8; ++k) {
        vals[k] = __expf(vals[k] - mx);
        sum += vals[k];
    }
    for (int d = 1; d < 64; d <<= 1) sum += __shfl_xor(sum, d);
    if ((tid & 63) == 0) reds[wv] = sum;
    __syncthreads();
    sum = reds[0] + reds[1] + reds[2] + reds[3];
    float inv = 1.0f / sum;
#pragma unroll
    for (int k = 0; k < 8; ++k) out[b * SEQ + k * 256 + tid] = vals[k] * inv;
}

// ---------------------------------------------------------------------------
extern "C" void kernel_launch(void* const* d_in, const int* in_sizes, int n_in,
                              void* d_out, int out_size, void* d_ws, size_t ws_size,
                              hipStream_t stream) {
    const float* hidden = (const float*)d_in[0];
    const float* enc    = (const float*)d_in[1];
    const float* W      = (const float*)d_in[2];
    const float* bias   = (const float*)d_in[3];
    const float* v      = (const float*)d_in[4];
    float* out = (float*)d_out;

    char* ws = (char*)d_ws;
    _Float16* packB = (_Float16*)ws;                              // 4 MiB
    float* hp       = (float*)(ws + (4u << 20));                  // 128 KiB
    float* score    = (float*)(ws + (4u << 20) + (128u << 10));   // 256 KiB

    pack_b_kernel<<<1024, 256, 0, stream>>>(W, packB);
    hproj_kernel<<<dim3(32, 16), 256, 0, stream>>>(hidden, W, bias, hp);
    attn_gemm_kernel<<<MTOT / 64, 512, 0, stream>>>(enc, packB, hp, v, score);
    softmax_kernel<<<BAT, 256, 0, stream>>>(score, out);
}